// Round 1
// baseline (712.918 us; speedup 1.0000x reference)
//
#include <hip/hip_runtime.h>
#include <math.h>

// ---------- types ----------
typedef __attribute__((ext_vector_type(8))) short short8;   // 8 bf16 (4 VGPRs)
typedef __attribute__((ext_vector_type(4))) float f32x4;    // MFMA acc

static __device__ __forceinline__ short f2bf(float f) {
  union { float f; unsigned u; } v; v.f = f;
  unsigned r = v.u + 0x7fffu + ((v.u >> 16) & 1u);  // RNE
  return (short)(r >> 16);
}
static __device__ __forceinline__ float bf2f(short s) {
  union { unsigned u; float f; } v; v.u = ((unsigned)(unsigned short)s) << 16;
  return v.f;
}
static __device__ __forceinline__ float gelu_exact(float x) {
  return 0.5f * x * (1.0f + erff(x * 0.70710678118654752f));
}
static __device__ __forceinline__ f32x4 mfma16(short8 a, short8 b, f32x4 c) {
  return __builtin_amdgcn_mfma_f32_16x16x32_bf16(a, b, c, 0, 0, 0);
}

// ---------- weight transpose + f32->bf16 ----------
// dst[c][r] = (bf16) src[r][c];  R,C multiples of 32
__global__ __launch_bounds__(256) void tcvt(const float* __restrict__ src,
                                            short* __restrict__ dst,
                                            int R, int C) {
  __shared__ float t[32][33];
  int c0 = blockIdx.x * 32, r0 = blockIdx.y * 32;
  int tx = threadIdx.x & 31, ty = threadIdx.x >> 5;  // 32x8
#pragma unroll
  for (int i = 0; i < 32; i += 8)
    t[ty + i][tx] = src[(long)(r0 + ty + i) * C + c0 + tx];
  __syncthreads();
#pragma unroll
  for (int i = 0; i < 32; i += 8)
    dst[(long)(c0 + ty + i) * R + r0 + tx] = f2bf(t[tx][ty + i]);
}

// ---------- LayerNorm (D=512), one wave per row, bf16 out ----------
__global__ __launch_bounds__(256) void ln_kernel(const float* __restrict__ x,
                                                 const float* __restrict__ gamma,
                                                 const float* __restrict__ beta,
                                                 short* __restrict__ out) {
  int row = blockIdx.x * 4 + (threadIdx.x >> 6);
  int lane = threadIdx.x & 63;
  const float* xr = x + (long)row * 512 + lane * 8;
  float v[8];
  *(f32x4*)&v[0] = *(const f32x4*)&xr[0];
  *(f32x4*)&v[4] = *(const f32x4*)&xr[4];
  float s = 0.f, ss = 0.f;
#pragma unroll
  for (int i = 0; i < 8; i++) { s += v[i]; ss += v[i] * v[i]; }
#pragma unroll
  for (int off = 1; off < 64; off <<= 1) {
    s += __shfl_xor(s, off);
    ss += __shfl_xor(ss, off);
  }
  float mu = s * (1.0f / 512.0f);
  float var = ss * (1.0f / 512.0f) - mu * mu;
  float rstd = rsqrtf(var + 1e-5f);
  float gv[8], bv[8];
  *(f32x4*)&gv[0] = *(const f32x4*)&gamma[lane * 8];
  *(f32x4*)&gv[4] = *(const f32x4*)&gamma[lane * 8 + 4];
  *(f32x4*)&bv[0] = *(const f32x4*)&beta[lane * 8];
  *(f32x4*)&bv[4] = *(const f32x4*)&beta[lane * 8 + 4];
  short8 o;
#pragma unroll
  for (int i = 0; i < 8; i++) o[i] = f2bf((v[i] - mu) * rstd * gv[i] + bv[i]);
  *(short8*)(out + (long)row * 512 + lane * 8) = o;
}

// ---------- softmax over rows of 2048, in-place on bf16 ----------
__global__ __launch_bounds__(256) void softmax_kernel(short* __restrict__ sb) {
  int row = blockIdx.x * 4 + (threadIdx.x >> 6);
  int lane = threadIdx.x & 63;
  short* p = sb + (long)row * 2048;
  float v[32];
#pragma unroll
  for (int c = 0; c < 4; c++) {
    short8 raw = *(const short8*)&p[(c * 64 + lane) * 8];
#pragma unroll
    for (int k = 0; k < 8; k++) v[c * 8 + k] = bf2f(raw[k]);
  }
  float mx = v[0];
#pragma unroll
  for (int i = 1; i < 32; i++) mx = fmaxf(mx, v[i]);
#pragma unroll
  for (int off = 1; off < 64; off <<= 1) mx = fmaxf(mx, __shfl_xor(mx, off));
  float sum = 0.f;
#pragma unroll
  for (int i = 0; i < 32; i++) { v[i] = __expf(v[i] - mx); sum += v[i]; }
#pragma unroll
  for (int off = 1; off < 64; off <<= 1) sum += __shfl_xor(sum, off);
  float inv = 1.0f / sum;
#pragma unroll
  for (int c = 0; c < 4; c++) {
    short8 o;
#pragma unroll
    for (int k = 0; k < 8; k++) o[k] = f2bf(v[c * 8 + k] * inv);
    *(short8*)&p[(c * 64 + lane) * 8] = o;
  }
}

// ---------- GEMM: C[M,N] = A[M,K] @ BT[N,K]^T  (bf16 in, f32 acc) ----------
// EPI: 0 = bf16 C        1 = bf16 C*scale (scores)
//      2 = bf16 vT write: vT[(mm>>11)*512*2048 + nn*2048 + (mm&2047)]
//      3 = f32  C = acc + (bias?bias[nn]:0) + resid[mm*N+nn]
//      4 = bf16 C = gelu(acc + bias[nn])
template <int EPI>
__global__ __launch_bounds__(256) void gemm_bt(
    const short* __restrict__ A, const short* __restrict__ BT,
    const int M, const int N, const int K,
    short* __restrict__ Cb, float* __restrict__ Cf,
    const float* __restrict__ bias, const float* __restrict__ resid,
    const float scale) {
  constexpr int LDT = 40;  // 32 + 8 pad (bf16), row = 80B (16B-aligned)
  __shared__ __align__(16) short As[64 * LDT];
  __shared__ __align__(16) short Bs[64 * LDT];

  const int m0 = blockIdx.y * 64, n0 = blockIdx.x * 64;
  const int tid = threadIdx.x;
  const int lane = tid & 63;
  const int wave = tid >> 6;
  const int r = lane & 15, g = lane >> 4;
  const int wm = (wave >> 1) * 32, wn = (wave & 1) * 32;
  const int srow = tid >> 2, skg = (tid & 3) * 8;

  f32x4 acc[2][2] = {};
  const long abase = (long)(m0 + srow) * K + skg;
  const long bbase = (long)(n0 + srow) * K + skg;

  for (int k0 = 0; k0 < K; k0 += 32) {
    *(short8*)&As[srow * LDT + skg] = *(const short8*)&A[abase + k0];
    *(short8*)&Bs[srow * LDT + skg] = *(const short8*)&BT[bbase + k0];
    __syncthreads();
    short8 a0 = *(const short8*)&As[(wm + r) * LDT + g * 8];
    short8 a1 = *(const short8*)&As[(wm + 16 + r) * LDT + g * 8];
    short8 b0 = *(const short8*)&Bs[(wn + r) * LDT + g * 8];
    short8 b1 = *(const short8*)&Bs[(wn + 16 + r) * LDT + g * 8];
    acc[0][0] = mfma16(a0, b0, acc[0][0]);
    acc[0][1] = mfma16(a0, b1, acc[0][1]);
    acc[1][0] = mfma16(a1, b0, acc[1][0]);
    acc[1][1] = mfma16(a1, b1, acc[1][1]);
    __syncthreads();
  }

#pragma unroll
  for (int i = 0; i < 2; i++)
#pragma unroll
    for (int j = 0; j < 2; j++) {
      const int mb = m0 + wm + i * 16 + g * 4;
      const int nn = n0 + wn + j * 16 + r;
#pragma unroll
      for (int q = 0; q < 4; q++) {
        const int mm = mb + q;
        const float val = acc[i][j][q];
        if (EPI == 0) {
          Cb[(long)mm * N + nn] = f2bf(val);
        } else if (EPI == 1) {
          Cb[(long)mm * N + nn] = f2bf(val * scale);
        } else if (EPI == 2) {
          Cb[(long)(mm >> 11) * (512 * 2048) + (long)nn * 2048 + (mm & 2047)] =
              f2bf(val);
        } else if (EPI == 3) {
          float vv = val + (bias ? bias[nn] : 0.0f) + resid[(long)mm * N + nn];
          Cf[(long)mm * N + nn] = vv;
        } else if (EPI == 4) {
          Cb[(long)mm * N + nn] = f2bf(gelu_exact(val + bias[nn]));
        }
      }
    }
}

// ---------- launch ----------
extern "C" void kernel_launch(void* const* d_in, const int* in_sizes, int n_in,
                              void* d_out, int out_size, void* d_ws,
                              size_t ws_size, hipStream_t stream) {
  const float* x   = (const float*)d_in[0];
  const float* Wq  = (const float*)d_in[1];
  const float* Wk  = (const float*)d_in[2];
  const float* Wv  = (const float*)d_in[3];
  const float* Wo  = (const float*)d_in[4];
  const float* W1  = (const float*)d_in[5];
  const float* b1  = (const float*)d_in[6];
  const float* W2  = (const float*)d_in[7];
  const float* b2  = (const float*)d_in[8];
  const float* g1  = (const float*)d_in[9];
  const float* be1 = (const float*)d_in[10];
  const float* g2  = (const float*)d_in[11];
  const float* be2 = (const float*)d_in[12];
  float* out = (float*)d_out;

  char* w = (char*)d_ws;
  auto alloc = [&](size_t bytes) {
    char* p = w;
    w += (bytes + 255) & ~(size_t)255;
    return p;
  };
  short* WqT = (short*)alloc(512 * 512 * 2);
  short* WkT = (short*)alloc(512 * 512 * 2);
  short* WvT = (short*)alloc(512 * 512 * 2);
  short* WoT = (short*)alloc(512 * 512 * 2);
  short* W1T = (short*)alloc(2048L * 512 * 2);   // [F][D]
  short* W2T = (short*)alloc(512L * 2048 * 2);   // [D][F]
  short* hb  = (short*)alloc(16384L * 512 * 2);  // LN1 out; reused as h2b
  short* qb  = (short*)alloc(16384L * 512 * 2);  // reused as attnb
  short* kb  = (short*)alloc(16384L * 512 * 2);
  short* vT  = (short*)alloc(16384L * 512 * 2);  // per-batch [512][2048]
  float* x2  = (float*)alloc(16384L * 512 * 4);
  short* big = (short*)alloc(16384L * 2048 * 2); // sb (per batch) / ffb
  short* sb = big;
  short* ffb = big;
  short* attnb = qb;
  short* h2b = hb;

  const float scale = 0.044194173824159216f;  // 1/sqrt(512)

  // weights -> bf16, transposed to [out][in]
  tcvt<<<dim3(16, 16), 256, 0, stream>>>(Wq, WqT, 512, 512);
  tcvt<<<dim3(16, 16), 256, 0, stream>>>(Wk, WkT, 512, 512);
  tcvt<<<dim3(16, 16), 256, 0, stream>>>(Wv, WvT, 512, 512);
  tcvt<<<dim3(16, 16), 256, 0, stream>>>(Wo, WoT, 512, 512);
  tcvt<<<dim3(64, 16), 256, 0, stream>>>(W1, W1T, 512, 2048);
  tcvt<<<dim3(16, 64), 256, 0, stream>>>(W2, W2T, 2048, 512);

  // LN1
  ln_kernel<<<4096, 256, 0, stream>>>(x, g1, be1, hb);

  // q, k, v
  gemm_bt<0><<<dim3(8, 256), 256, 0, stream>>>(hb, WqT, 16384, 512, 512, qb,
                                               nullptr, nullptr, nullptr, 0.f);
  gemm_bt<0><<<dim3(8, 256), 256, 0, stream>>>(hb, WkT, 16384, 512, 512, kb,
                                               nullptr, nullptr, nullptr, 0.f);
  gemm_bt<2><<<dim3(8, 256), 256, 0, stream>>>(hb, WvT, 16384, 512, 512, vT,
                                               nullptr, nullptr, nullptr, 0.f);

  // attention per batch (scores buffer reused)
  for (int b = 0; b < 8; b++) {
    const short* qp = qb + (long)b * 2048 * 512;
    const short* kp = kb + (long)b * 2048 * 512;
    const short* vp = vT + (long)b * 512 * 2048;
    short* ap = attnb + (long)b * 2048 * 512;
    gemm_bt<1><<<dim3(32, 32), 256, 0, stream>>>(qp, kp, 2048, 2048, 512, sb,
                                                 nullptr, nullptr, nullptr,
                                                 scale);
    softmax_kernel<<<512, 256, 0, stream>>>(sb);
    gemm_bt<0><<<dim3(8, 32), 256, 0, stream>>>(sb, vp, 2048, 512, 2048, ap,
                                                nullptr, nullptr, nullptr, 0.f);
  }

  // x2 = x + attn @ Wo
  gemm_bt<3><<<dim3(8, 256), 256, 0, stream>>>(attnb, WoT, 16384, 512, 512,
                                               nullptr, x2, nullptr, x, 0.f);

  // LN2
  ln_kernel<<<4096, 256, 0, stream>>>(x2, g2, be2, h2b);

  // ff = gelu(h2 @ W1 + b1)
  gemm_bt<4><<<dim3(32, 256), 256, 0, stream>>>(h2b, W1T, 16384, 2048, 512,
                                                ffb, nullptr, b1, nullptr, 0.f);

  // out = x2 + ff @ W2 + b2
  gemm_bt<3><<<dim3(8, 256), 256, 0, stream>>>(ffb, W2T, 16384, 512, 2048,
                                               nullptr, out, b2, x2, 0.f);
}

// Round 2
// 416.412 us; speedup vs baseline: 1.7121x; 1.7121x over previous
//
#include <hip/hip_runtime.h>
#include <math.h>

// ---------- types ----------
typedef __attribute__((ext_vector_type(8))) short short8;   // 8 bf16 (4 VGPRs)
typedef __attribute__((ext_vector_type(4))) float f32x4;    // MFMA acc

static __device__ __forceinline__ short f2bf(float f) {
  union { float f; unsigned u; } v; v.f = f;
  unsigned r = v.u + 0x7fffu + ((v.u >> 16) & 1u);  // RNE
  return (short)(r >> 16);
}
static __device__ __forceinline__ float bf2f(short s) {
  union { unsigned u; float f; } v; v.u = ((unsigned)(unsigned short)s) << 16;
  return v.f;
}
static __device__ __forceinline__ float gelu_exact(float x) {
  return 0.5f * x * (1.0f + erff(x * 0.70710678118654752f));
}
static __device__ __forceinline__ f32x4 mfma16(short8 a, short8 b, f32x4 c) {
  return __builtin_amdgcn_mfma_f32_16x16x32_bf16(a, b, c, 0, 0, 0);
}
static __device__ __forceinline__ void gload16(const short* g, short* l) {
  __builtin_amdgcn_global_load_lds(
      (const __attribute__((address_space(1))) void*)g,
      (__attribute__((address_space(3))) void*)l, 16, 0, 0);
}

// ---------- weight transpose + f32->bf16 ----------
__global__ __launch_bounds__(256) void tcvt(const float* __restrict__ src,
                                            short* __restrict__ dst,
                                            int R, int C) {
  __shared__ float t[32][33];
  int c0 = blockIdx.x * 32, r0 = blockIdx.y * 32;
  int tx = threadIdx.x & 31, ty = threadIdx.x >> 5;  // 32x8
#pragma unroll
  for (int i = 0; i < 32; i += 8)
    t[ty + i][tx] = src[(long)(r0 + ty + i) * C + c0 + tx];
  __syncthreads();
#pragma unroll
  for (int i = 0; i < 32; i += 8)
    dst[(long)(c0 + ty + i) * R + r0 + tx] = f2bf(t[tx][ty + i]);
}

// ---------- LayerNorm (D=512), one wave per row, bf16 out ----------
__global__ __launch_bounds__(256) void ln_kernel(const float* __restrict__ x,
                                                 const float* __restrict__ gamma,
                                                 const float* __restrict__ beta,
                                                 short* __restrict__ out) {
  int row = blockIdx.x * 4 + (threadIdx.x >> 6);
  int lane = threadIdx.x & 63;
  const float* xr = x + (long)row * 512 + lane * 8;
  float v[8];
  *(f32x4*)&v[0] = *(const f32x4*)&xr[0];
  *(f32x4*)&v[4] = *(const f32x4*)&xr[4];
  float s = 0.f, ss = 0.f;
#pragma unroll
  for (int i = 0; i < 8; i++) { s += v[i]; ss += v[i] * v[i]; }
#pragma unroll
  for (int off = 1; off < 64; off <<= 1) {
    s += __shfl_xor(s, off);
    ss += __shfl_xor(ss, off);
  }
  float mu = s * (1.0f / 512.0f);
  float var = ss * (1.0f / 512.0f) - mu * mu;
  float rstd = rsqrtf(var + 1e-5f);
  float gv[8], bv[8];
  *(f32x4*)&gv[0] = *(const f32x4*)&gamma[lane * 8];
  *(f32x4*)&gv[4] = *(const f32x4*)&gamma[lane * 8 + 4];
  *(f32x4*)&bv[0] = *(const f32x4*)&beta[lane * 8];
  *(f32x4*)&bv[4] = *(const f32x4*)&beta[lane * 8 + 4];
  short8 o;
#pragma unroll
  for (int i = 0; i < 8; i++) o[i] = f2bf((v[i] - mu) * rstd * gv[i] + bv[i]);
  *(short8*)(out + (long)row * 512 + lane * 8) = o;
}

// ---------- softmax over rows of 2048, in-place on bf16 ----------
__global__ __launch_bounds__(256) void softmax_kernel(short* __restrict__ sb) {
  int row = blockIdx.x * 4 + (threadIdx.x >> 6);
  int lane = threadIdx.x & 63;
  short* p = sb + (long)row * 2048;
  float v[32];
#pragma unroll
  for (int c = 0; c < 4; c++) {
    short8 raw = *(const short8*)&p[(c * 64 + lane) * 8];
#pragma unroll
    for (int k = 0; k < 8; k++) v[c * 8 + k] = bf2f(raw[k]);
  }
  float mx = v[0];
#pragma unroll
  for (int i = 1; i < 32; i++) mx = fmaxf(mx, v[i]);
#pragma unroll
  for (int off = 1; off < 64; off <<= 1) mx = fmaxf(mx, __shfl_xor(mx, off));
  float sum = 0.f;
#pragma unroll
  for (int i = 0; i < 32; i++) { v[i] = __expf(v[i] - mx); sum += v[i]; }
#pragma unroll
  for (int off = 1; off < 64; off <<= 1) sum += __shfl_xor(sum, off);
  float inv = 1.0f / sum;
#pragma unroll
  for (int c = 0; c < 4; c++) {
    short8 o;
#pragma unroll
    for (int k = 0; k < 8; k++) o[k] = f2bf(v[c * 8 + k] * inv);
    *(short8*)&p[(c * 64 + lane) * 8] = o;
  }
}

// ---------- GEMM (m97 structure): C[M,N] = A[M,K] @ BT[N,K]^T ----------
// 128x128 tile, BK=32, 4 waves x (64x64 out), global_load_lds width 16.
// EPI: 0 = bf16 C        1 = bf16 C*scale (scores)
//      2 = bf16 vT write: vT[(mm>>11)*512*2048 + nn*2048 + (mm&2047)]
//      3 = f32  C = acc + (bias?bias[nn]:0) + resid[mm*N+nn]
//      4 = bf16 C = gelu(acc + bias[nn])
template <int EPI>
__global__ __launch_bounds__(256) void gemm_bt(
    const short* __restrict__ A0, const short* __restrict__ BT0,
    const int M, const int N, const int K,
    short* __restrict__ Cb, float* __restrict__ Cf,
    const float* __restrict__ bias, const float* __restrict__ resid,
    const float scale,
    const long sA, const long sB, const long sC) {
  __shared__ __align__(16) short As[128 * 32];
  __shared__ __align__(16) short Bs[128 * 32];

  const int z = blockIdx.z;
  const short* A = A0 + (long)z * sA;
  const short* BT = BT0 + (long)z * sB;

  const int m0 = blockIdx.y * 128, n0 = blockIdx.x * 128;
  const int tid = threadIdx.x;
  const int lane = tid & 63;
  const int wave = tid >> 6;
  const int r = lane & 15, g = lane >> 4;
  const int wm = (wave >> 1) * 64, wn = (wave & 1) * 64;

  // staging: each thread loads 16B; 2 issues per tile (rows 0-63, 64-127)
  const int rowa = tid >> 2;           // 0..63
  const int cola = (tid & 3) * 8;      // element offset
  const short* gA = A + (long)(m0 + rowa) * K + cola;
  const short* gA2 = gA + (long)64 * K;
  const short* gB = BT + (long)(n0 + rowa) * K + cola;
  const short* gB2 = gB + (long)64 * K;
  short* lA = &As[rowa * 32 + cola];
  short* lA2 = &As[(rowa + 64) * 32 + cola];
  short* lB = &Bs[rowa * 32 + cola];
  short* lB2 = &Bs[(rowa + 64) * 32 + cola];

  f32x4 acc[4][4] = {};

  for (int k0 = 0; k0 < K; k0 += 32) {
    gload16(gA + k0, lA);
    gload16(gA2 + k0, lA2);
    gload16(gB + k0, lB);
    gload16(gB2 + k0, lB2);
    __syncthreads();
    short8 av[4], bv[4];
#pragma unroll
    for (int i = 0; i < 4; i++)
      av[i] = *(const short8*)&As[(wm + i * 16 + r) * 32 + g * 8];
#pragma unroll
    for (int j = 0; j < 4; j++)
      bv[j] = *(const short8*)&Bs[(wn + j * 16 + r) * 32 + g * 8];
#pragma unroll
    for (int i = 0; i < 4; i++)
#pragma unroll
      for (int j = 0; j < 4; j++)
        acc[i][j] = mfma16(av[i], bv[j], acc[i][j]);
    __syncthreads();
  }

#pragma unroll
  for (int i = 0; i < 4; i++)
#pragma unroll
    for (int j = 0; j < 4; j++) {
      const int mb = m0 + wm + i * 16 + g * 4;
      const int nn = n0 + wn + j * 16 + r;
#pragma unroll
      for (int q = 0; q < 4; q++) {
        const int mm = mb + q;
        const float val = acc[i][j][q];
        if (EPI == 0) {
          Cb[(long)z * sC + (long)mm * N + nn] = f2bf(val);
        } else if (EPI == 1) {
          Cb[(long)z * sC + (long)mm * N + nn] = f2bf(val * scale);
        } else if (EPI == 2) {
          Cb[(long)(mm >> 11) * (512 * 2048) + (long)nn * 2048 + (mm & 2047)] =
              f2bf(val);
        } else if (EPI == 3) {
          float vv = val + (bias ? bias[nn] : 0.0f) + resid[(long)mm * N + nn];
          Cf[(long)mm * N + nn] = vv;
        } else if (EPI == 4) {
          Cb[(long)mm * N + nn] = f2bf(gelu_exact(val + bias[nn]));
        }
      }
    }
}

// ---------- launch ----------
extern "C" void kernel_launch(void* const* d_in, const int* in_sizes, int n_in,
                              void* d_out, int out_size, void* d_ws,
                              size_t ws_size, hipStream_t stream) {
  const float* x   = (const float*)d_in[0];
  const float* Wq  = (const float*)d_in[1];
  const float* Wk  = (const float*)d_in[2];
  const float* Wv  = (const float*)d_in[3];
  const float* Wo  = (const float*)d_in[4];
  const float* W1  = (const float*)d_in[5];
  const float* b1  = (const float*)d_in[6];
  const float* W2  = (const float*)d_in[7];
  const float* b2  = (const float*)d_in[8];
  const float* g1  = (const float*)d_in[9];
  const float* be1 = (const float*)d_in[10];
  const float* g2  = (const float*)d_in[11];
  const float* be2 = (const float*)d_in[12];
  float* out = (float*)d_out;

  char* w = (char*)d_ws;
  auto alloc = [&](size_t bytes) {
    char* p = w;
    w += (bytes + 255) & ~(size_t)255;
    return p;
  };
  short* WqT = (short*)alloc(512 * 512 * 2);
  short* WkT = (short*)alloc(512 * 512 * 2);
  short* WvT = (short*)alloc(512 * 512 * 2);
  short* WoT = (short*)alloc(512 * 512 * 2);
  short* W1T = (short*)alloc(2048L * 512 * 2);   // [F][D]
  short* W2T = (short*)alloc(512L * 2048 * 2);   // [D][F]
  short* hb  = (short*)alloc(16384L * 512 * 2);  // LN1 out; reused as h2b
  short* qb  = (short*)alloc(16384L * 512 * 2);  // reused as attnb
  short* kb  = (short*)alloc(16384L * 512 * 2);
  short* vT  = (short*)alloc(16384L * 512 * 2);  // per-batch [512][2048]
  float* x2  = (float*)alloc(16384L * 512 * 4);
  short* big = (short*)alloc(16384L * 2048 * 2); // sb (all batches) / ffb
  short* sb = big;                                // 8 x [2048][2048] bf16
  short* ffb = big;
  short* attnb = qb;
  short* h2b = hb;

  const float scale = 0.044194173824159216f;  // 1/sqrt(512)

  // weights -> bf16, transposed to [out][in]
  tcvt<<<dim3(16, 16), 256, 0, stream>>>(Wq, WqT, 512, 512);
  tcvt<<<dim3(16, 16), 256, 0, stream>>>(Wk, WkT, 512, 512);
  tcvt<<<dim3(16, 16), 256, 0, stream>>>(Wv, WvT, 512, 512);
  tcvt<<<dim3(16, 16), 256, 0, stream>>>(Wo, WoT, 512, 512);
  tcvt<<<dim3(64, 16), 256, 0, stream>>>(W1, W1T, 512, 2048);
  tcvt<<<dim3(16, 64), 256, 0, stream>>>(W2, W2T, 2048, 512);

  // LN1
  ln_kernel<<<4096, 256, 0, stream>>>(x, g1, be1, hb);

  // q, k, v  (M=16384, N=512, K=512) grid (4,128)
  gemm_bt<0><<<dim3(4, 128), 256, 0, stream>>>(hb, WqT, 16384, 512, 512, qb,
                                               nullptr, nullptr, nullptr, 0.f,
                                               0, 0, 0);
  gemm_bt<0><<<dim3(4, 128), 256, 0, stream>>>(hb, WkT, 16384, 512, 512, kb,
                                               nullptr, nullptr, nullptr, 0.f,
                                               0, 0, 0);
  gemm_bt<2><<<dim3(4, 128), 256, 0, stream>>>(hb, WvT, 16384, 512, 512, vT,
                                               nullptr, nullptr, nullptr, 0.f,
                                               0, 0, 0);

  // scores: per-batch 2048x2048x512, batched via z  (grid 16,16,8)
  gemm_bt<1><<<dim3(16, 16, 8), 256, 0, stream>>>(
      qb, kb, 2048, 2048, 512, sb, nullptr, nullptr, nullptr, scale,
      2048L * 512, 2048L * 512, 2048L * 2048);

  // softmax over all 16384 rows
  softmax_kernel<<<4096, 256, 0, stream>>>(sb);

  // attn = P @ V : per-batch 2048x512x2048, batched  (grid 4,16,8)
  gemm_bt<0><<<dim3(4, 16, 8), 256, 0, stream>>>(
      sb, vT, 2048, 512, 2048, attnb, nullptr, nullptr, nullptr, 0.f,
      2048L * 2048, 512L * 2048, 2048L * 512);

  // x2 = x + attn @ Wo
  gemm_bt<3><<<dim3(4, 128), 256, 0, stream>>>(attnb, WoT, 16384, 512, 512,
                                               nullptr, x2, nullptr, x, 0.f,
                                               0, 0, 0);

  // LN2
  ln_kernel<<<4096, 256, 0, stream>>>(x2, g2, be2, h2b);

  // ff = gelu(h2 @ W1 + b1)   (M=16384, N=2048, K=512) grid (16,128)
  gemm_bt<4><<<dim3(16, 128), 256, 0, stream>>>(h2b, W1T, 16384, 2048, 512,
                                                ffb, nullptr, b1, nullptr, 0.f,
                                                0, 0, 0);

  // out = x2 + ff @ W2 + b2   (M=16384, N=512, K=2048) grid (4,128)
  gemm_bt<3><<<dim3(4, 128), 256, 0, stream>>>(ffb, W2T, 16384, 512, 2048,
                                               nullptr, out, b2, x2, 0.f,
                                               0, 0, 0);
}

// Round 3
// 409.868 us; speedup vs baseline: 1.7394x; 1.0160x over previous
//
#include <hip/hip_runtime.h>
#include <math.h>

// ---------- types ----------
typedef __attribute__((ext_vector_type(8))) short short8;   // 8 bf16 (4 VGPRs)
typedef __attribute__((ext_vector_type(4))) float f32x4;    // MFMA acc

static __device__ __forceinline__ short f2bf(float f) {
  union { float f; unsigned u; } v; v.f = f;
  unsigned r = v.u + 0x7fffu + ((v.u >> 16) & 1u);  // RNE
  return (short)(r >> 16);
}
static __device__ __forceinline__ float bf2f(short s) {
  union { unsigned u; float f; } v; v.u = ((unsigned)(unsigned short)s) << 16;
  return v.f;
}
static __device__ __forceinline__ float gelu_exact(float x) {
  return 0.5f * x * (1.0f + erff(x * 0.70710678118654752f));
}
static __device__ __forceinline__ f32x4 mfma16(short8 a, short8 b, f32x4 c) {
  return __builtin_amdgcn_mfma_f32_16x16x32_bf16(a, b, c, 0, 0, 0);
}
static __device__ __forceinline__ void gload16(const short* g, short* l) {
  __builtin_amdgcn_global_load_lds(
      (const __attribute__((address_space(1))) void*)g,
      (__attribute__((address_space(3))) void*)l, 16, 0, 0);
}

// ---------- weight transpose + f32->bf16 ----------
__global__ __launch_bounds__(256) void tcvt(const float* __restrict__ src,
                                            short* __restrict__ dst,
                                            int R, int C) {
  __shared__ float t[32][33];
  int c0 = blockIdx.x * 32, r0 = blockIdx.y * 32;
  int tx = threadIdx.x & 31, ty = threadIdx.x >> 5;  // 32x8
#pragma unroll
  for (int i = 0; i < 32; i += 8)
    t[ty + i][tx] = src[(long)(r0 + ty + i) * C + c0 + tx];
  __syncthreads();
#pragma unroll
  for (int i = 0; i < 32; i += 8)
    dst[(long)(c0 + ty + i) * R + r0 + tx] = f2bf(t[tx][ty + i]);
}

// ---------- LayerNorm (D=512), one wave per row, bf16 out ----------
__global__ __launch_bounds__(256) void ln_kernel(const float* __restrict__ x,
                                                 const float* __restrict__ gamma,
                                                 const float* __restrict__ beta,
                                                 short* __restrict__ out) {
  int row = blockIdx.x * 4 + (threadIdx.x >> 6);
  int lane = threadIdx.x & 63;
  const float* xr = x + (long)row * 512 + lane * 8;
  float v[8];
  *(f32x4*)&v[0] = *(const f32x4*)&xr[0];
  *(f32x4*)&v[4] = *(const f32x4*)&xr[4];
  float s = 0.f, ss = 0.f;
#pragma unroll
  for (int i = 0; i < 8; i++) { s += v[i]; ss += v[i] * v[i]; }
#pragma unroll
  for (int off = 1; off < 64; off <<= 1) {
    s += __shfl_xor(s, off);
    ss += __shfl_xor(ss, off);
  }
  float mu = s * (1.0f / 512.0f);
  float var = ss * (1.0f / 512.0f) - mu * mu;
  float rstd = rsqrtf(var + 1e-5f);
  float gv[8], bv[8];
  *(f32x4*)&gv[0] = *(const f32x4*)&gamma[lane * 8];
  *(f32x4*)&gv[4] = *(const f32x4*)&gamma[lane * 8 + 4];
  *(f32x4*)&bv[0] = *(const f32x4*)&beta[lane * 8];
  *(f32x4*)&bv[4] = *(const f32x4*)&beta[lane * 8 + 4];
  short8 o;
#pragma unroll
  for (int i = 0; i < 8; i++) o[i] = f2bf((v[i] - mu) * rstd * gv[i] + bv[i]);
  *(short8*)(out + (long)row * 512 + lane * 8) = o;
}

// ---------- softmax over rows of 2048, in-place on bf16 ----------
__global__ __launch_bounds__(256) void softmax_kernel(short* __restrict__ sb) {
  int row = blockIdx.x * 4 + (threadIdx.x >> 6);
  int lane = threadIdx.x & 63;
  short* p = sb + (long)row * 2048;
  float v[32];
#pragma unroll
  for (int c = 0; c < 4; c++) {
    short8 raw = *(const short8*)&p[(c * 64 + lane) * 8];
#pragma unroll
    for (int k = 0; k < 8; k++) v[c * 8 + k] = bf2f(raw[k]);
  }
  float mx = v[0];
#pragma unroll
  for (int i = 1; i < 32; i++) mx = fmaxf(mx, v[i]);
#pragma unroll
  for (int off = 1; off < 64; off <<= 1) mx = fmaxf(mx, __shfl_xor(mx, off));
  float sum = 0.f;
#pragma unroll
  for (int i = 0; i < 32; i++) { v[i] = __expf(v[i] - mx); sum += v[i]; }
#pragma unroll
  for (int off = 1; off < 64; off <<= 1) sum += __shfl_xor(sum, off);
  float inv = 1.0f / sum;
#pragma unroll
  for (int c = 0; c < 4; c++) {
    short8 o;
#pragma unroll
    for (int k = 0; k < 8; k++) o[k] = f2bf(v[c * 8 + k] * inv);
    *(short8*)&p[(c * 64 + lane) * 8] = o;
  }
}

// ---------- GEMM (2-phase dbuf): C[M,N] = A[M,K] @ BT[N,K]^T ----------
// 128x128 tile, BK=32, 4 waves x (64x64 out), global_load_lds width 16,
// double-buffered LDS: stage(t+1) issued before compute(t), 1 barrier/iter.
// EPI: 0 = bf16 C        1 = bf16 C*scale (scores)
//      3 = f32  C = acc + (bias?bias[nn]:0) + resid[mm*N+nn]
//      4 = bf16 C = gelu(acc + bias[nn])
//      5 = fused qkv: nn<512 -> q, nn<1024 -> k, else vT transposed write
template <int EPI>
__global__ __launch_bounds__(256) void gemm_bt(
    const short* __restrict__ A0, const short* __restrict__ BT0,
    const int M, const int N, const int K,
    short* __restrict__ Cb, short* __restrict__ Cb2, short* __restrict__ Cb3,
    float* __restrict__ Cf,
    const float* __restrict__ bias, const float* __restrict__ resid,
    const float scale,
    const long sA, const long sB, const long sC) {
  __shared__ __align__(16) short As[2][128 * 32];
  __shared__ __align__(16) short Bs[2][128 * 32];

  const int z = blockIdx.z;
  const short* A = A0 + (long)z * sA;
  const short* BT = BT0 + (long)z * sB;

  const int m0 = blockIdx.y * 128, n0 = blockIdx.x * 128;
  const int tid = threadIdx.x;
  const int lane = tid & 63;
  const int wave = tid >> 6;
  const int r = lane & 15, g = lane >> 4;
  const int wm = (wave >> 1) * 64, wn = (wave & 1) * 64;

  // staging: each thread loads 16B; 2 issues per operand tile
  const int rowa = tid >> 2;           // 0..63
  const int cola = (tid & 3) * 8;      // element offset
  const short* gA = A + (long)(m0 + rowa) * K + cola;
  const short* gA2 = gA + (long)64 * K;
  const short* gB = BT + (long)(n0 + rowa) * K + cola;
  const short* gB2 = gB + (long)64 * K;
  const int loff = rowa * 32 + cola;
  const int loff2 = (rowa + 64) * 32 + cola;

  f32x4 acc[4][4] = {};
  const int nt = K >> 5;

  // prologue: stage tile 0 into buffer 0
  gload16(gA, &As[0][loff]);
  gload16(gA2, &As[0][loff2]);
  gload16(gB, &Bs[0][loff]);
  gload16(gB2, &Bs[0][loff2]);
  __syncthreads();

  int cur = 0;
  for (int t = 0; t < nt; ++t) {
    if (t + 1 < nt) {
      const int k0 = (t + 1) << 5;
      gload16(gA + k0, &As[cur ^ 1][loff]);
      gload16(gA2 + k0, &As[cur ^ 1][loff2]);
      gload16(gB + k0, &Bs[cur ^ 1][loff]);
      gload16(gB2 + k0, &Bs[cur ^ 1][loff2]);
    }
    short8 av[4], bv[4];
#pragma unroll
    for (int i = 0; i < 4; i++)
      av[i] = *(const short8*)&As[cur][(wm + i * 16 + r) * 32 + g * 8];
#pragma unroll
    for (int j = 0; j < 4; j++)
      bv[j] = *(const short8*)&Bs[cur][(wn + j * 16 + r) * 32 + g * 8];
#pragma unroll
    for (int i = 0; i < 4; i++)
#pragma unroll
      for (int j = 0; j < 4; j++)
        acc[i][j] = mfma16(av[i], bv[j], acc[i][j]);
    __syncthreads();
    cur ^= 1;
  }

#pragma unroll
  for (int i = 0; i < 4; i++)
#pragma unroll
    for (int j = 0; j < 4; j++) {
      const int mb = m0 + wm + i * 16 + g * 4;
      const int nn = n0 + wn + j * 16 + r;
#pragma unroll
      for (int q = 0; q < 4; q++) {
        const int mm = mb + q;
        const float val = acc[i][j][q];
        if (EPI == 0) {
          Cb[(long)z * sC + (long)mm * N + nn] = f2bf(val);
        } else if (EPI == 1) {
          Cb[(long)z * sC + (long)mm * N + nn] = f2bf(val * scale);
        } else if (EPI == 3) {
          float vv = val + (bias ? bias[nn] : 0.0f) + resid[(long)mm * N + nn];
          Cf[(long)mm * N + nn] = vv;
        } else if (EPI == 4) {
          Cb[(long)mm * N + nn] = f2bf(gelu_exact(val + bias[nn]));
        } else if (EPI == 5) {
          const int sel = nn >> 9, c = nn & 511;  // block-uniform sel
          if (sel == 0) {
            Cb[(long)mm * 512 + c] = f2bf(val);
          } else if (sel == 1) {
            Cb2[(long)mm * 512 + c] = f2bf(val);
          } else {
            Cb3[(long)(mm >> 11) * (512 * 2048) + (long)c * 2048 +
                (mm & 2047)] = f2bf(val);
          }
        }
      }
    }
}

// ---------- launch ----------
extern "C" void kernel_launch(void* const* d_in, const int* in_sizes, int n_in,
                              void* d_out, int out_size, void* d_ws,
                              size_t ws_size, hipStream_t stream) {
  const float* x   = (const float*)d_in[0];
  const float* Wq  = (const float*)d_in[1];
  const float* Wk  = (const float*)d_in[2];
  const float* Wv  = (const float*)d_in[3];
  const float* Wo  = (const float*)d_in[4];
  const float* W1  = (const float*)d_in[5];
  const float* b1  = (const float*)d_in[6];
  const float* W2  = (const float*)d_in[7];
  const float* b2  = (const float*)d_in[8];
  const float* g1  = (const float*)d_in[9];
  const float* be1 = (const float*)d_in[10];
  const float* g2  = (const float*)d_in[11];
  const float* be2 = (const float*)d_in[12];
  float* out = (float*)d_out;

  char* w = (char*)d_ws;
  auto alloc = [&](size_t bytes) {
    char* p = w;
    w += (bytes + 255) & ~(size_t)255;
    return p;
  };
  short* WqkvT = (short*)alloc(1536L * 512 * 2); // [1536][512]: q,k,v stacked
  short* WoT = (short*)alloc(512 * 512 * 2);
  short* W1T = (short*)alloc(2048L * 512 * 2);   // [F][D]
  short* W2T = (short*)alloc(512L * 2048 * 2);   // [D][F]
  short* hb  = (short*)alloc(16384L * 512 * 2);  // LN1 out; reused as h2b
  short* qb  = (short*)alloc(16384L * 512 * 2);  // reused as attnb
  short* kb  = (short*)alloc(16384L * 512 * 2);
  short* vT  = (short*)alloc(16384L * 512 * 2);  // per-batch [512][2048]
  float* x2  = (float*)alloc(16384L * 512 * 4);
  short* big = (short*)alloc(16384L * 2048 * 2); // sb (all batches) / ffb
  short* sb = big;                                // 8 x [2048][2048] bf16
  short* ffb = big;
  short* attnb = qb;
  short* h2b = hb;

  const float scale = 0.044194173824159216f;  // 1/sqrt(512)

  // weights -> bf16, transposed to [out][in]
  tcvt<<<dim3(16, 16), 256, 0, stream>>>(Wq, WqkvT, 512, 512);
  tcvt<<<dim3(16, 16), 256, 0, stream>>>(Wk, WqkvT + 512L * 512, 512, 512);
  tcvt<<<dim3(16, 16), 256, 0, stream>>>(Wv, WqkvT + 1024L * 512, 512, 512);
  tcvt<<<dim3(16, 16), 256, 0, stream>>>(Wo, WoT, 512, 512);
  tcvt<<<dim3(64, 16), 256, 0, stream>>>(W1, W1T, 512, 2048);
  tcvt<<<dim3(16, 64), 256, 0, stream>>>(W2, W2T, 2048, 512);

  // LN1
  ln_kernel<<<4096, 256, 0, stream>>>(x, g1, be1, hb);

  // fused q,k,v  (M=16384, N=1536, K=512) grid (12,128)
  gemm_bt<5><<<dim3(12, 128), 256, 0, stream>>>(
      hb, WqkvT, 16384, 1536, 512, qb, kb, vT, nullptr, nullptr, nullptr, 0.f,
      0, 0, 0);

  // scores: per-batch 2048x2048x512, batched via z  (grid 16,16,8)
  gemm_bt<1><<<dim3(16, 16, 8), 256, 0, stream>>>(
      qb, kb, 2048, 2048, 512, sb, nullptr, nullptr, nullptr, nullptr, nullptr,
      scale, 2048L * 512, 2048L * 512, 2048L * 2048);

  // softmax over all 16384 rows
  softmax_kernel<<<4096, 256, 0, stream>>>(sb);

  // attn = P @ V : per-batch 2048x512x2048, batched  (grid 4,16,8)
  gemm_bt<0><<<dim3(4, 16, 8), 256, 0, stream>>>(
      sb, vT, 2048, 512, 2048, attnb, nullptr, nullptr, nullptr, nullptr,
      nullptr, 0.f, 2048L * 2048, 512L * 2048, 2048L * 512);

  // x2 = x + attn @ Wo
  gemm_bt<3><<<dim3(4, 128), 256, 0, stream>>>(
      attnb, WoT, 16384, 512, 512, nullptr, nullptr, nullptr, x2, nullptr, x,
      0.f, 0, 0, 0);

  // LN2
  ln_kernel<<<4096, 256, 0, stream>>>(x2, g2, be2, h2b);

  // ff = gelu(h2 @ W1 + b1)   (M=16384, N=2048, K=512) grid (16,128)
  gemm_bt<4><<<dim3(16, 128), 256, 0, stream>>>(
      h2b, W1T, 16384, 2048, 512, ffb, nullptr, nullptr, nullptr, b1, nullptr,
      0.f, 0, 0, 0);

  // out = x2 + ff @ W2 + b2   (M=16384, N=512, K=2048) grid (4,128)
  gemm_bt<3><<<dim3(4, 128), 256, 0, stream>>>(
      ffb, W2T, 16384, 512, 2048, nullptr, nullptr, nullptr, out, b2, x2, 0.f,
      0, 0, 0);
}